// Round 2
// baseline (1677.097 us; speedup 1.0000x reference)
//
#include <hip/hip_runtime.h>

// GraphTripleConvNet: 5 linear layers. bf16 MFMA GEMMs; pooling done in h-space
// (linearity: segment_sum(h@W2s) == segment_sum(h)@W2s) via deterministic CSR.
// Workspace: ~159 MB.

#define NTRI 60000
#define NOBJ 20000
#define DD 256
#define HH 512

typedef __attribute__((ext_vector_type(8))) short bf16x8;
typedef __attribute__((ext_vector_type(4))) float f32x4;

#define GLDS(gp, lp) __builtin_amdgcn_global_load_lds( \
    (const __attribute__((address_space(1))) void*)(gp), \
    (__attribute__((address_space(3))) void*)(lp), 16, 0, 0)

__device__ __forceinline__ unsigned short f2bf(float f){
  unsigned int x = __builtin_bit_cast(unsigned int, f);
  x += 0x7fffu + ((x >> 16) & 1u);   // RNE; data is small/finite
  return (unsigned short)(x >> 16);
}
__device__ __forceinline__ float bf2f(unsigned short u){
  return __builtin_bit_cast(float, (unsigned int)u << 16);
}

// ---------------------------------------------------------------------------
// GEMM: C(MxN) = A(MxK,bf16) @ Bt(NxK,bf16)^T [+ bias].
// 128x128 tile, BK=32, 4 waves, 4x4 mfma_f32_16x16x32_bf16 per wave.
// MODE 0: bf16 out (+bias). MODE 1: fp32 out (+bias). MODE 4: fp32 out, no bias.
// GATHER: A row r = concat(obj[eidx[r].x], pred[r], obj[eidx[r].y]), K must be 768.
// ---------------------------------------------------------------------------
template<int MODE, int GATHER>
__global__ __launch_bounds__(256) void gemm_k(
    const unsigned short* __restrict__ A,   // GATHER: obj_bf base (NOBJ x 256)
    const unsigned short* __restrict__ A2,  // GATHER: pred_bf base (NTRI x 256)
    const int2* __restrict__ eidx,
    const unsigned short* __restrict__ Bt,
    const float* __restrict__ bias,
    void* __restrict__ out0,
    int M, int K, int N)
{
  __shared__ unsigned short sA[128*32];
  __shared__ unsigned short sB[128*32];
  const int tid  = threadIdx.x;
  const int lane = tid & 63;
  const int wv   = tid >> 6;
  const int wm   = wv & 1;
  const int wn   = wv >> 1;
  const int quad = lane >> 4;
  const int l15  = lane & 15;
  const int m0 = blockIdx.y * 128;
  const int n0 = blockIdx.x * 128;

  f32x4 acc[4][4] = {};

  // staging: 16B chunk c -> LDS row c>>2, kpart c&3; c = tid and tid+256.
  // LDS side is wave-uniform base + lane*16 (required); global side is per-lane.
  const int r0 = m0 + (tid >> 2);
  const int r1 = r0 + 64;
  const int ra0 = (r0 < M) ? r0 : (M - 1);   // clamped; stores guarded
  const int ra1 = (r1 < M) ? r1 : (M - 1);
  const int kp = (tid & 3) * 8;

  const unsigned short *gA0 = nullptr, *gA1 = nullptr;
  const unsigned short *pS0 = nullptr, *pP0 = nullptr, *pO0 = nullptr;
  const unsigned short *pS1 = nullptr, *pP1 = nullptr, *pO1 = nullptr;
  if constexpr (GATHER){
    const int2 e0 = eidx[ra0], e1 = eidx[ra1];
    pS0 = A  + (size_t)e0.x * DD;  pP0 = A2 + (size_t)ra0 * DD;  pO0 = A + (size_t)e0.y * DD;
    pS1 = A  + (size_t)e1.x * DD;  pP1 = A2 + (size_t)ra1 * DD;  pO1 = A + (size_t)e1.y * DD;
  } else {
    gA0 = A + (size_t)ra0 * K + kp;
    gA1 = A + (size_t)ra1 * K + kp;
  }
  const unsigned short* gB0 = Bt + (size_t)(n0 + (tid >> 2)) * K + kp;
  const unsigned short* gB1 = Bt + (size_t)(n0 + 64 + (tid >> 2)) * K + kp;
  unsigned short* lA0 = sA + tid * 8;
  unsigned short* lA1 = sA + (tid + 256) * 8;
  unsigned short* lB0 = sB + tid * 8;
  unsigned short* lB1 = sB + (tid + 256) * 8;

  for (int k0 = 0; k0 < K; k0 += 32){
    __syncthreads();
    if constexpr (GATHER){
      const int c = k0 + kp;   // 8-col chunk lies fully inside one 256-wide segment
      const unsigned short* s0 = (c < DD) ? pS0 + c : ((c < 2*DD) ? pP0 + (c - DD) : pO0 + (c - 2*DD));
      const unsigned short* s1 = (c < DD) ? pS1 + c : ((c < 2*DD) ? pP1 + (c - DD) : pO1 + (c - 2*DD));
      GLDS(s0, lA0); GLDS(s1, lA1);
    } else {
      GLDS(gA0, lA0); GLDS(gA1, lA1);
      gA0 += 32; gA1 += 32;
    }
    GLDS(gB0, lB0); GLDS(gB1, lB1);
    gB0 += 32; gB1 += 32;
    __syncthreads();
    bf16x8 af[4], bq[4];
#pragma unroll
    for (int mt = 0; mt < 4; ++mt)   // A frag: m = l15, k = quad*8 + j
      af[mt] = *(const bf16x8*)(sA + (wm*64 + mt*16 + l15)*32 + quad*8);
#pragma unroll
    for (int nt = 0; nt < 4; ++nt)   // B frag: n = l15 (Bt rows are n)
      bq[nt] = *(const bf16x8*)(sB + (wn*64 + nt*16 + l15)*32 + quad*8);
#pragma unroll
    for (int mt = 0; mt < 4; ++mt)
#pragma unroll
      for (int nt = 0; nt < 4; ++nt)
        acc[mt][nt] = __builtin_amdgcn_mfma_f32_16x16x32_bf16(af[mt], bq[nt], acc[mt][nt], 0, 0, 0);
  }

  // C/D layout: col = l15, row = quad*4 + reg   [m89-verified]
#pragma unroll
  for (int mt = 0; mt < 4; ++mt){
    const int rb = m0 + wm*64 + mt*16 + quad*4;
#pragma unroll
    for (int nt = 0; nt < 4; ++nt){
      const int col = n0 + wn*64 + nt*16 + l15;
      const float bv = (MODE == 4) ? 0.f : bias[col];
#pragma unroll
      for (int r = 0; r < 4; ++r){
        const int row = rb + r;
        if (row >= M) continue;
        const float v = acc[mt][nt][r] + bv;
        if constexpr (MODE == 0) ((unsigned short*)out0)[(size_t)row * N + col] = f2bf(v);
        else                     ((float*)out0)[(size_t)row * N + col] = v;
      }
    }
  }
}

// --- edges dtype autodetect: int64 rows have zero high words at odd int32 slots ---
__global__ __launch_bounds__(256) void detect_k(const int* __restrict__ e, int* __restrict__ flag)
{
  const int i = blockIdx.x * 256 + threadIdx.x;
  if (i >= NTRI) return;
  if (e[2*i + 1] != 0) atomicOr(flag, 1);   // any nonzero odd word => int32 layout
}

__global__ __launch_bounds__(256) void norm_k(const int* __restrict__ e, const int* __restrict__ flag,
                                              int2* __restrict__ eidx)
{
  const int i = blockIdx.x * 256 + threadIdx.x;
  if (i >= NTRI) return;
  int s, o;
  if (*flag){ s = e[2*i]; o = e[2*i + 1]; }      // int32: (s,o) packed
  else      { s = e[4*i]; o = e[4*i + 2]; }      // int64: low words
  s = min(max(s, 0), NOBJ - 1);
  o = min(max(o, 0), NOBJ - 1);
  eidx[i] = make_int2(s, o);
}

__global__ __launch_bounds__(256) void deg_k(const int2* __restrict__ eidx,
                                             int* __restrict__ cnt_s, int* __restrict__ cnt_o)
{
  const int i = blockIdx.x * 256 + threadIdx.x;
  if (i >= NTRI) return;
  atomicAdd(&cnt_s[eidx[i].x], 1);
  atomicAdd(&cnt_o[eidx[i].y], 1);
}

// exclusive scan of (cnt_s+cnt_o) -> offs[0..NOBJ], single block
__global__ __launch_bounds__(1024) void scan_k(const int* __restrict__ cnt_s,
                                               const int* __restrict__ cnt_o,
                                               int* __restrict__ offs)
{
  __shared__ int sd[1024];
  __shared__ int carry;
  if (threadIdx.x == 0) carry = 0;
  __syncthreads();
  const int nIter = (NOBJ + 1023) / 1024;
  for (int it = 0; it < nIter; ++it){
    const int i = it * 1024 + (int)threadIdx.x;
    const int v = (i < NOBJ) ? (cnt_s[i] + cnt_o[i]) : 0;
    sd[threadIdx.x] = v;
    __syncthreads();
    for (int off = 1; off < 1024; off <<= 1){
      const int t = ((int)threadIdx.x >= off) ? sd[threadIdx.x - off] : 0;
      __syncthreads();
      sd[threadIdx.x] += t;
      __syncthreads();
    }
    if (i < NOBJ) offs[i] = carry + sd[threadIdx.x] - v;
    __syncthreads();
    if (threadIdx.x == 0){
      carry += sd[1023];
      if (it == nIter - 1) offs[NOBJ] = carry;
    }
    __syncthreads();
  }
}

__global__ __launch_bounds__(256) void fill_k(const int2* __restrict__ eidx,
                                              int* __restrict__ cursor, int* __restrict__ slots)
{
  const int i = blockIdx.x * 256 + threadIdx.x;
  if (i >= NTRI) return;
  slots[atomicAdd(&cursor[eidx[i].x], 1)] = 2*i;       // even = subject role
  slots[atomicAdd(&cursor[eidx[i].y], 1)] = 2*i + 1;   // odd  = object role
}

// hSO[o] = [ sum_{subject slots} h[e] (512) | sum_{object slots} h[e] (512) ] -> bf16
__global__ __launch_bounds__(256) void pool_h_k(
    const unsigned short* __restrict__ h, const int* __restrict__ offs,
    const int* __restrict__ slots, unsigned short* __restrict__ hSO)
{
  const int o = blockIdx.x;
  const int c = threadIdx.x;          // cols c and c+256
  const int b0 = offs[o], b1 = offs[o+1];
  float s0 = 0.f, s1 = 0.f, o0 = 0.f, o1 = 0.f;
  for (int j = b0; j < b1; ++j){
    const int sl = slots[j];
    const unsigned short* row = h + (size_t)(sl >> 1) * HH;
    const float v0 = bf2f(row[c]);
    const float v1 = bf2f(row[c + 256]);
    if (sl & 1){ o0 += v0; o1 += v1; } else { s0 += v0; s1 += v1; }
  }
  unsigned short* dst = hSO + (size_t)o * 1024;
  dst[c]        = f2bf(s0);
  dst[c + 256]  = f2bf(s1);
  dst[c + 512]  = f2bf(o0);
  dst[c + 768]  = f2bf(o1);
}

// pooled_bf = (pre + ns*b2s + no*b2o) / max(ns+no,1)
__global__ __launch_bounds__(256) void divide_k(
    const float* __restrict__ pre, const int* __restrict__ cnt_s, const int* __restrict__ cnt_o,
    const float* __restrict__ b2s, const float* __restrict__ b2o,
    unsigned short* __restrict__ pooled)
{
  const int i2 = (blockIdx.x * 256 + threadIdx.x) * 2;
  if (i2 >= NOBJ * HH) return;
  const int o = i2 >> 9;
  const int c = i2 & 511;
  const float ns = (float)cnt_s[o], no = (float)cnt_o[o];
  const float inv = 1.f / fmaxf(ns + no, 1.f);
  const float2 v = *(const float2*)(pre + i2);
  ushort2 r;
  r.x = f2bf((v.x + ns * b2s[c]     + no * b2o[c])     * inv);
  r.y = f2bf((v.y + ns * b2s[c + 1] + no * b2o[c + 1]) * inv);
  *(ushort2*)(pooled + i2) = r;
}

// fp32 -> bf16 flat (vector x4)
__global__ __launch_bounds__(256) void conv_f2b_k(const float* __restrict__ x,
                                                  unsigned short* __restrict__ y, int n4)
{
  const int i = blockIdx.x * 256 + threadIdx.x;
  if (i >= n4) return;
  const float4 v = ((const float4*)x)[i];
  ushort4 r;
  r.x = f2bf(v.x); r.y = f2bf(v.y); r.z = f2bf(v.z); r.w = f2bf(v.w);
  ((ushort4*)y)[i] = r;
}

// Wt[n*ldK + kOff + k] = bf16(W[k*ldW + colOff + n]) over n<N, k<Kpart
__global__ __launch_bounds__(256) void conv_w_k(const float* __restrict__ W,
                                                unsigned short* __restrict__ Wt,
                                                int Kpart, int N, int ldW, int colOff,
                                                int ldK, int kOff)
{
  const int idx = blockIdx.x * 256 + threadIdx.x;
  if (idx >= N * Kpart) return;
  const int n = idx / Kpart;
  const int k = idx - n * Kpart;
  Wt[(size_t)n * ldK + kOff + k] = f2bf(W[(size_t)k * ldW + colOff + n]);
}

extern "C" void kernel_launch(void* const* d_in, const int* in_sizes, int n_in,
                              void* d_out, int out_size, void* d_ws, size_t ws_size,
                              hipStream_t stream)
{
  const float* obj_in  = (const float*)d_in[0];
  const float* pred_in = (const float*)d_in[1];
  const int*   edges   = (const int*)d_in[2];
  const float* W1 = (const float*)d_in[3];
  const float* b1 = (const float*)d_in[4];
  const float* W2 = (const float*)d_in[5];
  const float* b2 = (const float*)d_in[6];
  const float* W3 = (const float*)d_in[7];
  const float* b3 = (const float*)d_in[8];
  const float* W4 = (const float*)d_in[9];
  const float* b4 = (const float*)d_in[10];
  float* out = (float*)d_out;

  char* p = (char*)d_ws;
  auto alloc = [&](size_t bytes){ char* r = p; p += (bytes + 255) & ~(size_t)255; return r; };

  unsigned short *wt1[5], *wt2p[5], *wt2so[5], *wt3[5], *wt4[5];
  for (int l = 0; l < 5; ++l){
    wt1[l]   = (unsigned short*)alloc((size_t)512 * 768 * 2);
    wt2p[l]  = (unsigned short*)alloc((size_t)256 * 512 * 2);
    wt2so[l] = (unsigned short*)alloc((size_t)512 * 1024 * 2);
    wt3[l]   = (unsigned short*)alloc((size_t)512 * 512 * 2);
    wt4[l]   = (unsigned short*)alloc((size_t)256 * 512 * 2);
  }
  unsigned short* obj_bf  = (unsigned short*)alloc((size_t)NOBJ * DD * 2);   // 10.24 MB
  unsigned short* pred_bf = (unsigned short*)alloc((size_t)NTRI * DD * 2);   // 30.72 MB
  unsigned short* h       = (unsigned short*)alloc((size_t)NTRI * HH * 2);   // 61.44 MB
  unsigned short* hSO     = (unsigned short*)alloc((size_t)NOBJ * 1024 * 2); // 40.96 MB
  int2* eidx  = (int2*)alloc((size_t)NTRI * 8);
  int* offs   = (int*)alloc((NOBJ + 1) * 4);
  int* slots  = (int*)alloc(2 * NTRI * 4);
  int* cnt_s  = (int*)alloc(NOBJ * 4);
  int* cnt_o  = (int*)alloc(NOBJ * 4);
  int* cursor = (int*)alloc(NOBJ * 4);
  int* flag   = (int*)alloc(256);
  // aliases into dead regions:
  float*          pooled_pre = (float*)h;                                     // 40.96 MB (h dead)
  unsigned short* pooled_bf  = (unsigned short*)((char*)h + (size_t)NOBJ*HH*4); // 20.48 MB
  unsigned short* h2         = hSO;                                           // 20.48 MB (hSO dead)

  // ---- preamble (edges are layer-invariant) ----
  hipMemsetAsync(cnt_s, 0, NOBJ * 4, stream);
  hipMemsetAsync(cnt_o, 0, NOBJ * 4, stream);
  hipMemsetAsync(flag, 0, 4, stream);
  const int EB = (NTRI + 255) / 256;
  detect_k<<<EB, 256, 0, stream>>>(edges, flag);
  norm_k<<<EB, 256, 0, stream>>>(edges, flag, eidx);
  deg_k<<<EB, 256, 0, stream>>>(eidx, cnt_s, cnt_o);
  scan_k<<<1, 1024, 0, stream>>>(cnt_s, cnt_o, offs);
  hipMemcpyAsync(cursor, offs, NOBJ * 4, hipMemcpyDeviceToDevice, stream);
  fill_k<<<EB, 256, 0, stream>>>(eidx, cursor, slots);

  conv_f2b_k<<<(NOBJ * DD / 4 + 255) / 256, 256, 0, stream>>>(obj_in, obj_bf, NOBJ * DD / 4);
  conv_f2b_k<<<(NTRI * DD / 4 + 255) / 256, 256, 0, stream>>>(pred_in, pred_bf, NTRI * DD / 4);

  for (int l = 0; l < 5; ++l){
    conv_w_k<<<(768*512 + 255)/256, 256, 0, stream>>>(W1 + (size_t)l*768*512, wt1[l],   768, 512, 512, 0,   768, 0);
    conv_w_k<<<(512*256 + 255)/256, 256, 0, stream>>>(W2 + (size_t)l*512*1280, wt2p[l], 512, 256, 1280, 512, 512, 0);
    conv_w_k<<<(512*512 + 255)/256, 256, 0, stream>>>(W2 + (size_t)l*512*1280, wt2so[l],512, 512, 1280, 0,   1024, 0);
    conv_w_k<<<(512*512 + 255)/256, 256, 0, stream>>>(W2 + (size_t)l*512*1280, wt2so[l],512, 512, 1280, 768, 1024, 512);
    conv_w_k<<<(512*512 + 255)/256, 256, 0, stream>>>(W3 + (size_t)l*512*512, wt3[l],   512, 512, 512, 0,   512, 0);
    conv_w_k<<<(512*256 + 255)/256, 256, 0, stream>>>(W4 + (size_t)l*512*256, wt4[l],   512, 256, 256, 0,   512, 0);
  }

  for (int l = 0; l < 5; ++l){
    // h = concat(obj[s],pred,obj[o]) @ W1 + b1   (60000x768 @ 768x512 -> bf16)
    gemm_k<0,1><<<dim3(4, 469), 256, 0, stream>>>(obj_bf, pred_bf, eidx, wt1[l],
                                                  b1 + (size_t)l*HH, h, NTRI, 768, HH);
    // new_p = h @ W2[:,512:768] + b2[512:768]    (60000x512 @ 512x256)
    if (l < 4)
      gemm_k<0,0><<<dim3(2, 469), 256, 0, stream>>>(h, nullptr, nullptr, wt2p[l],
                                                    b2 + (size_t)l*1280 + HH, pred_bf, NTRI, HH, DD);
    else
      gemm_k<1,0><<<dim3(2, 469), 256, 0, stream>>>(h, nullptr, nullptr, wt2p[l],
                                                    b2 + (size_t)l*1280 + HH, out + (size_t)NOBJ*DD, NTRI, HH, DD);
    // hSO = CSR segment-sum of h, split by role    (-> 20000x1024 bf16)
    pool_h_k<<<NOBJ, 256, 0, stream>>>(h, offs, slots, hSO);
    // pooled_pre = hSO @ [W2s; W2o]               (20000x1024 @ 1024x512 -> fp32, no bias)
    gemm_k<4,0><<<dim3(4, 157), 256, 0, stream>>>(hSO, nullptr, nullptr, wt2so[l],
                                                  nullptr, pooled_pre, NOBJ, 1024, HH);
    // pooled = (pre + ns*b2s + no*b2o) / max(deg,1) -> bf16
    divide_k<<<(NOBJ*HH/2 + 255)/256, 256, 0, stream>>>(pooled_pre, cnt_s, cnt_o,
                                                        b2 + (size_t)l*1280, b2 + (size_t)l*1280 + 768,
                                                        pooled_bf);
    // h2 = pooled @ W3 + b3                       (20000x512 @ 512x512 -> bf16)
    gemm_k<0,0><<<dim3(4, 157), 256, 0, stream>>>(pooled_bf, nullptr, nullptr, wt3[l],
                                                  b3 + (size_t)l*HH, h2, NOBJ, HH, HH);
    // obj = h2 @ W4 + b4                          (20000x512 @ 512x256)
    if (l < 4)
      gemm_k<0,0><<<dim3(2, 157), 256, 0, stream>>>(h2, nullptr, nullptr, wt4[l],
                                                    b4 + (size_t)l*DD, obj_bf, NOBJ, HH, DD);
    else
      gemm_k<1,0><<<dim3(2, 157), 256, 0, stream>>>(h2, nullptr, nullptr, wt4[l],
                                                    b4 + (size_t)l*DD, out, NOBJ, HH, DD);
  }
}

// Round 3
// 1331.433 us; speedup vs baseline: 1.2596x; 1.2596x over previous
//
#include <hip/hip_runtime.h>

// GraphTripleConvNet: fully linear -> compose weights per layer.
//   pooled = [tS|tO] @ (W1@[W2s;W2o]) with deg-bias+divide fused in epilogue
//   new_p  = gather(t) @ (W1@W2p) + (b1@W2p+b2p)
//   new_o  = pooled @ (W3@W4) + (b3@W4+b4)
// Workspace ~151 MB.

#define NTRI 60000
#define NOBJ 20000
#define DD 256
#define HH 512

typedef __attribute__((ext_vector_type(8))) short bf16x8;
typedef __attribute__((ext_vector_type(4))) float f32x4;

#define GLDS(gp, lp) __builtin_amdgcn_global_load_lds( \
    (const __attribute__((address_space(1))) void*)(gp), \
    (__attribute__((address_space(3))) void*)(lp), 16, 0, 0)

__device__ __forceinline__ unsigned short f2bf(float f){
  unsigned int x = __builtin_bit_cast(unsigned int, f);
  x += 0x7fffu + ((x >> 16) & 1u);   // RNE
  return (unsigned short)(x >> 16);
}
__device__ __forceinline__ float bf2f(unsigned short u){
  return __builtin_bit_cast(float, (unsigned int)u << 16);
}

// ---------------------------------------------------------------------------
// C(MxN) = A(MxK,bf16) @ Bt(NxK,bf16)^T [+ epilogue].  128x128 tile, BK=32,
// 4 waves, 4x4 mfma_f32_16x16x32_bf16. grid.z batches (strides in elements).
// MODE 0: bf16 +bias.  MODE 1: fp32 +bias.
// MODE 2: bf16, v=(acc + ns*bias[col] + no*bias2[col]) / max(ns+no,1), ns/no per row.
// MODE 3: bf16 transposed store out[col*ldT+row], no bias (weight composition).
// GATHER: A row r = concat(obj[eidx[r].x], pred[r], obj[eidx[r].y]), K==768.
// ---------------------------------------------------------------------------
template<int MODE, int GATHER>
__global__ __launch_bounds__(256) void gemm_k(
    const unsigned short* __restrict__ A,
    const unsigned short* __restrict__ A2,
    const int2* __restrict__ eidx,
    const unsigned short* __restrict__ Bt,
    const float* __restrict__ bias,
    const float* __restrict__ bias2,
    const int* __restrict__ cntS,
    const int* __restrict__ cntO,
    void* __restrict__ out0,
    int M, int K, int N, int ldT,
    long strideA, long strideB, long strideC)
{
  __shared__ unsigned short sA[128*32];
  __shared__ unsigned short sB[128*32];
  const int tid  = threadIdx.x;
  const int lane = tid & 63;
  const int wv   = tid >> 6;
  const int wm   = wv & 1;
  const int wn   = wv >> 1;
  const int quad = lane >> 4;
  const int l15  = lane & 15;
  const int m0 = blockIdx.y * 128;
  const int n0 = blockIdx.x * 128;
  const size_t zb = blockIdx.z;
  A  += zb * strideA;
  Bt += zb * strideB;

  f32x4 acc[4][4] = {};

  const int r0 = m0 + (tid >> 2);
  const int r1 = r0 + 64;
  const int ra0 = (r0 < M) ? r0 : (M - 1);   // clamped; stores guarded
  const int ra1 = (r1 < M) ? r1 : (M - 1);
  const int kp = (tid & 3) * 8;

  const unsigned short *gA0 = nullptr, *gA1 = nullptr;
  const unsigned short *pS0 = nullptr, *pP0 = nullptr, *pO0 = nullptr;
  const unsigned short *pS1 = nullptr, *pP1 = nullptr, *pO1 = nullptr;
  if constexpr (GATHER){
    const int2 e0 = eidx[ra0], e1 = eidx[ra1];
    pS0 = A  + (size_t)e0.x * DD;  pP0 = A2 + (size_t)ra0 * DD;  pO0 = A + (size_t)e0.y * DD;
    pS1 = A  + (size_t)e1.x * DD;  pP1 = A2 + (size_t)ra1 * DD;  pO1 = A + (size_t)e1.y * DD;
  } else {
    gA0 = A + (size_t)ra0 * K + kp;
    gA1 = A + (size_t)ra1 * K + kp;
  }
  const unsigned short* gB0 = Bt + (size_t)(n0 + (tid >> 2)) * K + kp;
  const unsigned short* gB1 = Bt + (size_t)(n0 + 64 + (tid >> 2)) * K + kp;
  unsigned short* lA0 = sA + tid * 8;
  unsigned short* lA1 = sA + (tid + 256) * 8;
  unsigned short* lB0 = sB + tid * 8;
  unsigned short* lB1 = sB + (tid + 256) * 8;

  for (int k0 = 0; k0 < K; k0 += 32){
    __syncthreads();
    if constexpr (GATHER){
      const int c = k0 + kp;   // 8-col chunk lies inside one 256-wide segment
      const unsigned short* s0 = (c < DD) ? pS0 + c : ((c < 2*DD) ? pP0 + (c - DD) : pO0 + (c - 2*DD));
      const unsigned short* s1 = (c < DD) ? pS1 + c : ((c < 2*DD) ? pP1 + (c - DD) : pO1 + (c - 2*DD));
      GLDS(s0, lA0); GLDS(s1, lA1);
    } else {
      GLDS(gA0, lA0); GLDS(gA1, lA1);
      gA0 += 32; gA1 += 32;
    }
    GLDS(gB0, lB0); GLDS(gB1, lB1);
    gB0 += 32; gB1 += 32;
    __syncthreads();
    bf16x8 af[4], bq[4];
#pragma unroll
    for (int mt = 0; mt < 4; ++mt)   // A frag: m = l15, k = quad*8 + j
      af[mt] = *(const bf16x8*)(sA + (wm*64 + mt*16 + l15)*32 + quad*8);
#pragma unroll
    for (int nt = 0; nt < 4; ++nt)   // B frag: n = l15 (Bt rows are n)
      bq[nt] = *(const bf16x8*)(sB + (wn*64 + nt*16 + l15)*32 + quad*8);
#pragma unroll
    for (int mt = 0; mt < 4; ++mt)
#pragma unroll
      for (int nt = 0; nt < 4; ++nt)
        acc[mt][nt] = __builtin_amdgcn_mfma_f32_16x16x32_bf16(af[mt], bq[nt], acc[mt][nt], 0, 0, 0);
  }

  // C/D layout: col = l15, row = quad*4 + reg   [m89-verified]
  if constexpr (MODE == 3){
    unsigned short* outp = (unsigned short*)out0 + zb * strideC;
#pragma unroll
    for (int mt = 0; mt < 4; ++mt){
      const int rb = m0 + wm*64 + mt*16 + quad*4;
#pragma unroll
      for (int nt = 0; nt < 4; ++nt){
        const int col = n0 + wn*64 + nt*16 + l15;
        ushort4 r4;
        r4.x = f2bf(acc[mt][nt][0]); r4.y = f2bf(acc[mt][nt][1]);
        r4.z = f2bf(acc[mt][nt][2]); r4.w = f2bf(acc[mt][nt][3]);
        *(ushort4*)(outp + (size_t)col * ldT + rb) = r4;
      }
    }
  } else {
#pragma unroll
    for (int mt = 0; mt < 4; ++mt){
      const int rb = m0 + wm*64 + mt*16 + quad*4;
#pragma unroll
      for (int nt = 0; nt < 4; ++nt){
        const int col = n0 + wn*64 + nt*16 + l15;
        const float bv = (MODE == 2) ? 0.f : bias[col];
#pragma unroll
        for (int r = 0; r < 4; ++r){
          const int row = rb + r;
          if (row >= M) continue;
          if constexpr (MODE == 2){
            const float ns = (float)cntS[row], no = (float)cntO[row];
            const float v = (acc[mt][nt][r] + ns * bias[col] + no * bias2[col])
                            / fmaxf(ns + no, 1.f);
            ((unsigned short*)out0)[(size_t)row * N + col] = f2bf(v);
          } else {
            const float v = acc[mt][nt][r] + bv;
            if constexpr (MODE == 0) ((unsigned short*)out0)[(size_t)row * N + col] = f2bf(v);
            else                     ((float*)out0)[(size_t)row * N + col] = v;
          }
        }
      }
    }
  }
}

// --- edges dtype autodetect ---
__global__ __launch_bounds__(256) void detect_k(const int* __restrict__ e, int* __restrict__ flag)
{
  const int i = blockIdx.x * 256 + threadIdx.x;
  if (i >= NTRI) return;
  if (e[2*i + 1] != 0) atomicOr(flag, 1);   // any nonzero odd word => int32 layout
}

__global__ __launch_bounds__(256) void norm_k(const int* __restrict__ e, const int* __restrict__ flag,
                                              int2* __restrict__ eidx)
{
  const int i = blockIdx.x * 256 + threadIdx.x;
  if (i >= NTRI) return;
  int s, o;
  if (*flag){ s = e[2*i]; o = e[2*i + 1]; }
  else      { s = e[4*i]; o = e[4*i + 2]; }
  s = min(max(s, 0), NOBJ - 1);
  o = min(max(o, 0), NOBJ - 1);
  eidx[i] = make_int2(s, o);
}

__global__ __launch_bounds__(256) void deg_k(const int2* __restrict__ eidx,
                                             int* __restrict__ cnt_s, int* __restrict__ cnt_o)
{
  const int i = blockIdx.x * 256 + threadIdx.x;
  if (i >= NTRI) return;
  atomicAdd(&cnt_s[eidx[i].x], 1);
  atomicAdd(&cnt_o[eidx[i].y], 1);
}

__global__ __launch_bounds__(1024) void scan_k(const int* __restrict__ cnt_s,
                                               const int* __restrict__ cnt_o,
                                               int* __restrict__ offs)
{
  __shared__ int sd[1024];
  __shared__ int carry;
  if (threadIdx.x == 0) carry = 0;
  __syncthreads();
  const int nIter = (NOBJ + 1023) / 1024;
  for (int it = 0; it < nIter; ++it){
    const int i = it * 1024 + (int)threadIdx.x;
    const int v = (i < NOBJ) ? (cnt_s[i] + cnt_o[i]) : 0;
    sd[threadIdx.x] = v;
    __syncthreads();
    for (int off = 1; off < 1024; off <<= 1){
      const int t = ((int)threadIdx.x >= off) ? sd[threadIdx.x - off] : 0;
      __syncthreads();
      sd[threadIdx.x] += t;
      __syncthreads();
    }
    if (i < NOBJ) offs[i] = carry + sd[threadIdx.x] - v;
    __syncthreads();
    if (threadIdx.x == 0){
      carry += sd[1023];
      if (it == nIter - 1) offs[NOBJ] = carry;
    }
    __syncthreads();
  }
}

// slot payload: (2*e+role, other_object_index)
__global__ __launch_bounds__(256) void fill_k(const int2* __restrict__ eidx,
                                              int* __restrict__ cursor, int2* __restrict__ slots)
{
  const int i = blockIdx.x * 256 + threadIdx.x;
  if (i >= NTRI) return;
  const int2 e = eidx[i];
  slots[atomicAdd(&cursor[e.x], 1)] = make_int2(2*i,     e.y);   // subject role
  slots[atomicAdd(&cursor[e.y], 1)] = make_int2(2*i + 1, e.x);   // object role
}

// tSO[o][1536] = [ns*obj[o] | Σ_s pred | Σ_s obj[oidx] | Σ_o obj[sidx] | Σ_o pred | no*obj[o]]
__global__ __launch_bounds__(256) void pool_t_k(
    const unsigned short* __restrict__ obj, const unsigned short* __restrict__ pred,
    const int* __restrict__ offs, const int2* __restrict__ slots,
    const int* __restrict__ cnt_s, const int* __restrict__ cnt_o,
    unsigned short* __restrict__ tSO)
{
  const int o = blockIdx.x;
  const int c = threadIdx.x;
  const int b0 = offs[o], b1 = offs[o+1];
  float sp = 0.f, so = 0.f, oo = 0.f, op = 0.f;
  for (int j = b0; j < b1; ++j){
    const int2 sl = slots[j];
    const float pv = bf2f(pred[(size_t)(sl.x >> 1) * DD + c]);
    const float ov = bf2f(obj[(size_t)sl.y * DD + c]);
    if (sl.x & 1){ op += pv; oo += ov; } else { sp += pv; so += ov; }
  }
  const float ob = bf2f(obj[(size_t)o * DD + c]);
  const float ns = (float)cnt_s[o], no = (float)cnt_o[o];
  unsigned short* dst = tSO + (size_t)o * 1536;
  dst[c]        = f2bf(ns * ob);
  dst[c + 256]  = f2bf(sp);
  dst[c + 512]  = f2bf(so);
  dst[c + 768]  = f2bf(oo);
  dst[c + 1024] = f2bf(op);
  dst[c + 1280] = f2bf(no * ob);
}

// fp32 -> bf16 flat (vector x4)
__global__ __launch_bounds__(256) void conv_f2b_k(const float* __restrict__ x,
                                                  unsigned short* __restrict__ y, int n4)
{
  const int i = blockIdx.x * 256 + threadIdx.x;
  if (i >= n4) return;
  const float4 v = ((const float4*)x)[i];
  ushort4 r;
  r.x = f2bf(v.x); r.y = f2bf(v.y); r.z = f2bf(v.z); r.w = f2bf(v.w);
  ((ushort4*)y)[i] = r;
}

// batched (L=5) transpose-convert: Wt[l][n][k] = bf16(W[l][k][colOff+n]), K=512
__global__ __launch_bounds__(256) void conv_wT_k(
    const float* __restrict__ W, unsigned short* __restrict__ Wt,
    int N, int ldW, int colOff, long wLS, long oLS)
{
  const int idx = blockIdx.x * 256 + threadIdx.x;
  const int per = N * 512;
  if (idx >= 5 * per) return;
  const int l = idx / per;
  const int r = idx - l * per;
  const int n = r >> 9;
  const int k = r & 511;
  Wt[l * oLS + (size_t)n * 512 + k] = f2bf(W[l * wLS + (size_t)k * ldW + colOff + n]);
}

// bias composition: cb2[l][0..1280) = b1[l]@W2[l] + b2[l];  b34c[l][0..256) = b3[l]@W4[l] + b4[l]
__global__ __launch_bounds__(256) void biascomp_k(
    const float* __restrict__ b1, const float* __restrict__ W2, const float* __restrict__ b2,
    const float* __restrict__ b3, const float* __restrict__ W4, const float* __restrict__ b4,
    float* __restrict__ cb2, float* __restrict__ b34c)
{
  const int idx = blockIdx.x * 256 + threadIdx.x;
  if (idx < 5 * 1280){
    const int l = idx / 1280, n = idx - l * 1280;
    float s = b2[l * 1280 + n];
    for (int k = 0; k < 512; ++k)
      s += b1[l * 512 + k] * W2[(size_t)l * 512 * 1280 + (size_t)k * 1280 + n];
    cb2[idx] = s;
  } else if (idx < 5 * 1280 + 5 * 256){
    const int j = idx - 6400;
    const int l = j / 256, n = j - l * 256;
    float s = b4[l * 256 + n];
    for (int k = 0; k < 512; ++k)
      s += b3[l * 512 + k] * W4[(size_t)l * 512 * 256 + (size_t)k * 256 + n];
    b34c[j] = s;
  }
}

extern "C" void kernel_launch(void* const* d_in, const int* in_sizes, int n_in,
                              void* d_out, int out_size, void* d_ws, size_t ws_size,
                              hipStream_t stream)
{
  const float* obj_in  = (const float*)d_in[0];
  const float* pred_in = (const float*)d_in[1];
  const int*   edges   = (const int*)d_in[2];
  const float* W1 = (const float*)d_in[3];
  const float* b1 = (const float*)d_in[4];
  const float* W2 = (const float*)d_in[5];
  const float* b2 = (const float*)d_in[6];
  const float* W3 = (const float*)d_in[7];
  const float* b3 = (const float*)d_in[8];
  const float* W4 = (const float*)d_in[9];
  const float* b4 = (const float*)d_in[10];
  float* out = (float*)d_out;

  char* p = (char*)d_ws;
  auto alloc = [&](size_t bytes){ char* r = p; p += (bytes + 255) & ~(size_t)255; return r; };

  // staging converts (batched over 5 layers, contiguous)
  unsigned short* W1bf  = (unsigned short*)alloc((size_t)5 * 768 * 512 * 2);  // A of W1@*
  unsigned short* W2pT  = (unsigned short*)alloc((size_t)5 * 256 * 512 * 2);
  unsigned short* W2sT  = (unsigned short*)alloc((size_t)5 * 512 * 512 * 2);
  unsigned short* W2oT  = (unsigned short*)alloc((size_t)5 * 512 * 512 * 2);
  unsigned short* W3bf  = (unsigned short*)alloc((size_t)5 * 512 * 512 * 2);
  unsigned short* W4T   = (unsigned short*)alloc((size_t)5 * 256 * 512 * 2);
  // composed weights (Bt layout)
  unsigned short* W12pT = (unsigned short*)alloc((size_t)5 * 256 * 768 * 2);
  unsigned short* W12so = (unsigned short*)alloc((size_t)5 * 512 * 1536 * 2);
  unsigned short* W34T  = (unsigned short*)alloc((size_t)5 * 256 * 512 * 2);
  float* cb2  = (float*)alloc((size_t)5 * 1280 * 4);
  float* b34c = (float*)alloc((size_t)5 * 256 * 4);
  // activations
  unsigned short* obj_bf  = (unsigned short*)alloc((size_t)NOBJ * DD * 2);   // 10.2 MB
  unsigned short* pred_bf = (unsigned short*)alloc((size_t)NTRI * DD * 2);   // 30.7 MB
  unsigned short* tSO     = (unsigned short*)alloc((size_t)NOBJ * 1536 * 2); // 61.4 MB
  unsigned short* pooled  = (unsigned short*)alloc((size_t)NOBJ * HH * 2);   // 20.5 MB
  // CSR
  int2* eidx  = (int2*)alloc((size_t)NTRI * 8);
  int*  offs  = (int*)alloc((NOBJ + 1) * 4);
  int2* slots = (int2*)alloc((size_t)2 * NTRI * 8);
  int* cnt_s  = (int*)alloc(NOBJ * 4);
  int* cnt_o  = (int*)alloc(NOBJ * 4);
  int* cursor = (int*)alloc(NOBJ * 4);
  int* flag   = (int*)alloc(256);

  // ---- preamble: CSR (edges layer-invariant) ----
  hipMemsetAsync(cnt_s, 0, NOBJ * 4, stream);
  hipMemsetAsync(cnt_o, 0, NOBJ * 4, stream);
  hipMemsetAsync(flag, 0, 4, stream);
  const int EB = (NTRI + 255) / 256;
  detect_k<<<EB, 256, 0, stream>>>(edges, flag);
  norm_k<<<EB, 256, 0, stream>>>(edges, flag, eidx);
  deg_k<<<EB, 256, 0, stream>>>(eidx, cnt_s, cnt_o);
  scan_k<<<1, 1024, 0, stream>>>(cnt_s, cnt_o, offs);
  hipMemcpyAsync(cursor, offs, NOBJ * 4, hipMemcpyDeviceToDevice, stream);
  fill_k<<<EB, 256, 0, stream>>>(eidx, cursor, slots);

  // ---- preamble: inputs -> bf16 ----
  conv_f2b_k<<<(NOBJ * DD / 4 + 255) / 256, 256, 0, stream>>>(obj_in, obj_bf, NOBJ * DD / 4);
  conv_f2b_k<<<(NTRI * DD / 4 + 255) / 256, 256, 0, stream>>>(pred_in, pred_bf, NTRI * DD / 4);

  // ---- preamble: weight staging (batched) ----
  conv_f2b_k<<<(5 * 768 * 512 / 4 + 255) / 256, 256, 0, stream>>>(W1, W1bf, 5 * 768 * 512 / 4);
  conv_f2b_k<<<(5 * 512 * 512 / 4 + 255) / 256, 256, 0, stream>>>(W3, W3bf, 5 * 512 * 512 / 4);
  conv_wT_k<<<(5 * 256 * 512 + 255) / 256, 256, 0, stream>>>(W2, W2pT, 256, 1280, 512, 512L*1280, 256L*512);
  conv_wT_k<<<(5 * 512 * 512 + 255) / 256, 256, 0, stream>>>(W2, W2sT, 512, 1280, 0,   512L*1280, 512L*512);
  conv_wT_k<<<(5 * 512 * 512 + 255) / 256, 256, 0, stream>>>(W2, W2oT, 512, 1280, 768, 512L*1280, 512L*512);
  conv_wT_k<<<(5 * 256 * 512 + 255) / 256, 256, 0, stream>>>(W4, W4T,  256, 256,  0,   512L*256,  256L*512);
  biascomp_k<<<30, 256, 0, stream>>>(b1, W2, b2, b3, W4, b4, cb2, b34c);

  // ---- preamble: weight composition (MODE 3 transposed store, grid.z = 5) ----
  gemm_k<3,0><<<dim3(2, 6, 5), 256, 0, stream>>>(W1bf, nullptr, nullptr, W2pT, nullptr, nullptr,
      nullptr, nullptr, W12pT, 768, 512, 256, 768, 768L*512, 256L*512, 256L*768);
  gemm_k<3,0><<<dim3(4, 6, 5), 256, 0, stream>>>(W1bf, nullptr, nullptr, W2sT, nullptr, nullptr,
      nullptr, nullptr, W12so, 768, 512, 512, 1536, 768L*512, 512L*512, 512L*1536);
  gemm_k<3,0><<<dim3(4, 6, 5), 256, 0, stream>>>(W1bf, nullptr, nullptr, W2oT, nullptr, nullptr,
      nullptr, nullptr, W12so + 768, 768, 512, 512, 1536, 768L*512, 512L*512, 512L*1536);
  gemm_k<3,0><<<dim3(2, 4, 5), 256, 0, stream>>>(W3bf, nullptr, nullptr, W4T, nullptr, nullptr,
      nullptr, nullptr, W34T, 512, 512, 256, 512, 512L*512, 256L*512, 256L*512);

  // ---- layers ----
  for (int l = 0; l < 5; ++l){
    const unsigned short* w12so = W12so + (size_t)l * 512 * 1536;
    const unsigned short* w12pT = W12pT + (size_t)l * 256 * 768;
    const unsigned short* w34T  = W34T  + (size_t)l * 256 * 512;
    const float* c1   = cb2 + (size_t)l * 1280;        // b1@W2s + b2s
    const float* b12p = cb2 + (size_t)l * 1280 + 512;  // b1@W2p + b2p
    const float* c2   = cb2 + (size_t)l * 1280 + 768;  // b1@W2o + b2o
    const float* bo   = b34c + (size_t)l * 256;        // b3@W4 + b4

    // tSO = role-split segment sums of (obj, pred) in t-space
    pool_t_k<<<NOBJ, 256, 0, stream>>>(obj_bf, pred_bf, offs, slots, cnt_s, cnt_o, tSO);
    // pooled = (tSO @ W12so + ns*c1 + no*c2) / max(deg,1)   (20000x1536x512)
    gemm_k<2,0><<<dim3(4, 157), 256, 0, stream>>>(tSO, nullptr, nullptr, w12so, c1, c2,
        cnt_s, cnt_o, pooled, NOBJ, 1536, HH, 0, 0, 0, 0);
    // new_p = gather(t) @ W12p + b12p   (60000x768x256), in-place safe (row-disjoint)
    if (l < 4)
      gemm_k<0,1><<<dim3(2, 469), 256, 0, stream>>>(obj_bf, pred_bf, eidx, w12pT, b12p, nullptr,
          nullptr, nullptr, pred_bf, NTRI, 768, DD, 0, 0, 0, 0);
    else
      gemm_k<1,1><<<dim3(2, 469), 256, 0, stream>>>(obj_bf, pred_bf, eidx, w12pT, b12p, nullptr,
          nullptr, nullptr, out + (size_t)NOBJ * DD, NTRI, 768, DD, 0, 0, 0, 0);
    // new_o = pooled @ W34 + b34   (20000x512x256)
    if (l < 4)
      gemm_k<0,0><<<dim3(2, 157), 256, 0, stream>>>(pooled, nullptr, nullptr, w34T, bo, nullptr,
          nullptr, nullptr, obj_bf, NOBJ, HH, DD, 0, 0, 0, 0);
    else
      gemm_k<1,0><<<dim3(2, 157), 256, 0, stream>>>(pooled, nullptr, nullptr, w34T, bo, nullptr,
          nullptr, nullptr, out, NOBJ, HH, DD, 0, 0, 0, 0);
  }
}

// Round 5
// 1278.597 us; speedup vs baseline: 1.3117x; 1.0413x over previous
//
#include <hip/hip_runtime.h>

// GraphTripleConvNet, fully linear -> aggressive weight composition.
// Per layer:
//   pool_t : tSO[o] = [ns*obj|SUMs pred|SUMs obj[o']|SUMo obj[s']|SUMo pred|no*obj]
//   GEMM_A : new_obj = (tSO @ (W12so@W34) + ns*c1' + no*c2')/max(deg,1) + b34   (K=1536,N=256)
//   GEMM_C : objSO   = obj @ [Wp_s|Wp_o]                                        (K=256, N=512)
//   GEMM_B : predP   = pred @ Wp_p + b12p                                       (K=256, N=256)
//   add_k  : new_pred[e] = predP[e] + objSO[s_e][0:256] + objSO[o_e][256:512]
// Workspace ~144 MB.

#define NTRI 60000
#define NOBJ 20000
#define DD 256
#define HH 512

typedef __attribute__((ext_vector_type(8))) short bf16x8;
typedef __attribute__((ext_vector_type(4))) float f32x4;

#define GLDS(gp, lp) __builtin_amdgcn_global_load_lds( \
    (const __attribute__((address_space(1))) void*)(gp), \
    (__attribute__((address_space(3))) void*)(lp), 16, 0, 0)

__device__ __forceinline__ unsigned short f2bf(float f){
  unsigned int x = __builtin_bit_cast(unsigned int, f);
  x += 0x7fffu + ((x >> 16) & 1u);   // RNE
  return (unsigned short)(x >> 16);
}
__device__ __forceinline__ float bf2f(unsigned short u){
  return __builtin_bit_cast(float, (unsigned int)u << 16);
}

// ---------------------------------------------------------------------------
// C(MxN) = A(MxK,bf16) @ Bt(NxK,bf16)^T [+ epilogue].  128x128 tile, BK=32,
// 4 waves, 4x4 mfma_f32_16x16x32_bf16.  grid.z batching via strides (elements).
// MODE 0: bf16 + bias[col].
// MODE 2: bf16, v = (acc + ns*bias[col] + no*bias2[col])/max(ns+no,1) + bias3[col].
// MODE 6: fp32, same epilogue as MODE 2.
// MODE 3: bf16 transposed store out[col*ldT+row] (weight composition).
// MODE 5: bf16, no bias.
// ---------------------------------------------------------------------------
template<int MODE>
__global__ __launch_bounds__(256) void gemm_k(
    const unsigned short* __restrict__ A,
    const unsigned short* __restrict__ Bt,
    const float* __restrict__ bias,
    const float* __restrict__ bias2,
    const float* __restrict__ bias3,
    const int* __restrict__ cntS,
    const int* __restrict__ cntO,
    void* __restrict__ out0,
    int M, int K, int N, int ldT,
    long strideA, long strideB, long strideC)
{
  __shared__ unsigned short sA[128*32];
  __shared__ unsigned short sB[128*32];
  const int tid  = threadIdx.x;
  const int lane = tid & 63;
  const int wv   = tid >> 6;
  const int wm   = wv & 1;
  const int wn   = wv >> 1;
  const int quad = lane >> 4;
  const int l15  = lane & 15;
  const int m0 = blockIdx.y * 128;
  const int n0 = blockIdx.x * 128;
  const size_t zb = blockIdx.z;
  A  += zb * strideA;
  Bt += zb * strideB;

  f32x4 acc[4][4] = {};

  const int r0 = m0 + (tid >> 2);
  const int r1 = r0 + 64;
  const int ra0 = (r0 < M) ? r0 : (M - 1);   // clamped; stores guarded
  const int ra1 = (r1 < M) ? r1 : (M - 1);
  const int kp = (tid & 3) * 8;

  const unsigned short* gA0 = A + (size_t)ra0 * K + kp;
  const unsigned short* gA1 = A + (size_t)ra1 * K + kp;
  const unsigned short* gB0 = Bt + (size_t)(n0 + (tid >> 2)) * K + kp;
  const unsigned short* gB1 = Bt + (size_t)(n0 + 64 + (tid >> 2)) * K + kp;
  unsigned short* lA0 = sA + tid * 8;
  unsigned short* lA1 = sA + (tid + 256) * 8;
  unsigned short* lB0 = sB + tid * 8;
  unsigned short* lB1 = sB + (tid + 256) * 8;

  for (int k0 = 0; k0 < K; k0 += 32){
    __syncthreads();
    GLDS(gA0, lA0); GLDS(gA1, lA1);
    GLDS(gB0, lB0); GLDS(gB1, lB1);
    gA0 += 32; gA1 += 32; gB0 += 32; gB1 += 32;
    __syncthreads();
    bf16x8 af[4], bq[4];
#pragma unroll
    for (int mt = 0; mt < 4; ++mt)   // A frag: m = l15, k = quad*8 + j
      af[mt] = *(const bf16x8*)(sA + (wm*64 + mt*16 + l15)*32 + quad*8);
#pragma unroll
    for (int nt = 0; nt < 4; ++nt)   // B frag: n = l15 (Bt rows are n)
      bq[nt] = *(const bf16x8*)(sB + (wn*64 + nt*16 + l15)*32 + quad*8);
#pragma unroll
    for (int mt = 0; mt < 4; ++mt)
#pragma unroll
      for (int nt = 0; nt < 4; ++nt)
        acc[mt][nt] = __builtin_amdgcn_mfma_f32_16x16x32_bf16(af[mt], bq[nt], acc[mt][nt], 0, 0, 0);
  }

  // C/D layout: col = l15, row = quad*4 + reg   [m89-verified]
  if constexpr (MODE == 3){
    unsigned short* outp = (unsigned short*)out0 + zb * strideC;
#pragma unroll
    for (int mt = 0; mt < 4; ++mt){
      const int rb = m0 + wm*64 + mt*16 + quad*4;
#pragma unroll
      for (int nt = 0; nt < 4; ++nt){
        const int col = n0 + wn*64 + nt*16 + l15;
        ushort4 r4;
        r4.x = f2bf(acc[mt][nt][0]); r4.y = f2bf(acc[mt][nt][1]);
        r4.z = f2bf(acc[mt][nt][2]); r4.w = f2bf(acc[mt][nt][3]);
        *(ushort4*)(outp + (size_t)col * ldT + rb) = r4;
      }
    }
  } else {
    // NOTE: zb output offset applied here too (round-4 bug: MODE 5 with grid.z=5
    // raced all layers into layer-0's buffer). strideC is in elements.
    char* outp = (char*)out0 + zb * strideC * ((MODE == 6) ? 4 : 2);
#pragma unroll
    for (int mt = 0; mt < 4; ++mt){
      const int rb = m0 + wm*64 + mt*16 + quad*4;
#pragma unroll
      for (int nt = 0; nt < 4; ++nt){
        const int col = n0 + wn*64 + nt*16 + l15;
#pragma unroll
        for (int r = 0; r < 4; ++r){
          const int row = rb + r;
          if (row >= M) continue;
          float v = acc[mt][nt][r];
          if constexpr (MODE == 0) v += bias[col];
          if constexpr (MODE == 2 || MODE == 6){
            const float ns = (float)cntS[row], no = (float)cntO[row];
            v = (v + ns * bias[col] + no * bias2[col]) / fmaxf(ns + no, 1.f) + bias3[col];
          }
          if constexpr (MODE == 6) ((float*)outp)[(size_t)row * N + col] = v;
          else                     ((unsigned short*)outp)[(size_t)row * N + col] = f2bf(v);
        }
      }
    }
  }
}

// --- edges dtype autodetect ---
__global__ __launch_bounds__(256) void detect_k(const int* __restrict__ e, int* __restrict__ flag)
{
  const int i = blockIdx.x * 256 + threadIdx.x;
  if (i >= NTRI) return;
  if (e[2*i + 1] != 0) atomicOr(flag, 1);   // any nonzero odd word => int32 layout
}

__global__ __launch_bounds__(256) void norm_k(const int* __restrict__ e, const int* __restrict__ flag,
                                              int2* __restrict__ eidx)
{
  const int i = blockIdx.x * 256 + threadIdx.x;
  if (i >= NTRI) return;
  int s, o;
  if (*flag){ s = e[2*i]; o = e[2*i + 1]; }
  else      { s = e[4*i]; o = e[4*i + 2]; }
  s = min(max(s, 0), NOBJ - 1);
  o = min(max(o, 0), NOBJ - 1);
  eidx[i] = make_int2(s, o);
}

__global__ __launch_bounds__(256) void deg_k(const int2* __restrict__ eidx,
                                             int* __restrict__ cnt_s, int* __restrict__ cnt_o)
{
  const int i = blockIdx.x * 256 + threadIdx.x;
  if (i >= NTRI) return;
  atomicAdd(&cnt_s[eidx[i].x], 1);
  atomicAdd(&cnt_o[eidx[i].y], 1);
}

__global__ __launch_bounds__(1024) void scan_k(const int* __restrict__ cnt_s,
                                               const int* __restrict__ cnt_o,
                                               int* __restrict__ offs)
{
  __shared__ int sd[1024];
  __shared__ int carry;
  if (threadIdx.x == 0) carry = 0;
  __syncthreads();
  const int nIter = (NOBJ + 1023) / 1024;
  for (int it = 0; it < nIter; ++it){
    const int i = it * 1024 + (int)threadIdx.x;
    const int v = (i < NOBJ) ? (cnt_s[i] + cnt_o[i]) : 0;
    sd[threadIdx.x] = v;
    __syncthreads();
    for (int off = 1; off < 1024; off <<= 1){
      const int t = ((int)threadIdx.x >= off) ? sd[threadIdx.x - off] : 0;
      __syncthreads();
      sd[threadIdx.x] += t;
      __syncthreads();
    }
    if (i < NOBJ) offs[i] = carry + sd[threadIdx.x] - v;
    __syncthreads();
    if (threadIdx.x == 0){
      carry += sd[1023];
      if (it == nIter - 1) offs[NOBJ] = carry;
    }
    __syncthreads();
  }
}

// slot payload: (2*e+role, other_object_index)
__global__ __launch_bounds__(256) void fill_k(const int2* __restrict__ eidx,
                                              int* __restrict__ cursor, int2* __restrict__ slots)
{
  const int i = blockIdx.x * 256 + threadIdx.x;
  if (i >= NTRI) return;
  const int2 e = eidx[i];
  slots[atomicAdd(&cursor[e.x], 1)] = make_int2(2*i,     e.y);   // subject role
  slots[atomicAdd(&cursor[e.y], 1)] = make_int2(2*i + 1, e.x);   // object role
}

// tSO[o][1536] = [ns*obj[o] | SUMs pred | SUMs obj[oidx] | SUMo obj[sidx] | SUMo pred | no*obj[o]]
__global__ __launch_bounds__(256) void pool_t_k(
    const unsigned short* __restrict__ obj, const unsigned short* __restrict__ pred,
    const int* __restrict__ offs, const int2* __restrict__ slots,
    const int* __restrict__ cnt_s, const int* __restrict__ cnt_o,
    unsigned short* __restrict__ tSO)
{
  const int o = blockIdx.x;
  const int c = threadIdx.x;
  const int b0 = offs[o], b1 = offs[o+1];
  float sp = 0.f, so = 0.f, oo = 0.f, op = 0.f;
  for (int j = b0; j < b1; ++j){
    const int2 sl = slots[j];
    const float pv = bf2f(pred[(size_t)(sl.x >> 1) * DD + c]);
    const float ov = bf2f(obj[(size_t)sl.y * DD + c]);
    if (sl.x & 1){ op += pv; oo += ov; } else { sp += pv; so += ov; }
  }
  const float ob = bf2f(obj[(size_t)o * DD + c]);
  const float ns = (float)cnt_s[o], no = (float)cnt_o[o];
  unsigned short* dst = tSO + (size_t)o * 1536;
  dst[c]        = f2bf(ns * ob);
  dst[c + 256]  = f2bf(sp);
  dst[c + 512]  = f2bf(so);
  dst[c + 768]  = f2bf(oo);
  dst[c + 1024] = f2bf(op);
  dst[c + 1280] = f2bf(no * ob);
}

// new_pred[e][c] = predP[e][c] + objSO[s_e][c] + objSO[o_e][256+c]
template<int OUT>
__global__ __launch_bounds__(256) void add_k(
    const unsigned short* __restrict__ predP, const unsigned short* __restrict__ objSO,
    const int2* __restrict__ eidx, void* __restrict__ outp)
{
  const int i = blockIdx.x * 256 + threadIdx.x;
  if (i >= NTRI * 64) return;
  const int e  = i >> 6;
  const int c4 = (i & 63) << 2;
  const int2 ei = eidx[e];
  const ushort4 a = *(const ushort4*)(predP + (size_t)e * DD + c4);
  const ushort4 s = *(const ushort4*)(objSO + (size_t)ei.x * 512 + c4);
  const ushort4 o = *(const ushort4*)(objSO + (size_t)ei.y * 512 + 256 + c4);
  float v0 = bf2f(a.x) + bf2f(s.x) + bf2f(o.x);
  float v1 = bf2f(a.y) + bf2f(s.y) + bf2f(o.y);
  float v2 = bf2f(a.z) + bf2f(s.z) + bf2f(o.z);
  float v3 = bf2f(a.w) + bf2f(s.w) + bf2f(o.w);
  if constexpr (OUT){
    float4 r = make_float4(v0, v1, v2, v3);
    *(float4*)((float*)outp + (size_t)e * DD + c4) = r;
  } else {
    ushort4 r;
    r.x = f2bf(v0); r.y = f2bf(v1); r.z = f2bf(v2); r.w = f2bf(v3);
    *(ushort4*)((unsigned short*)outp + (size_t)e * DD + c4) = r;
  }
}

// fp32 -> bf16 flat (vector x4)
__global__ __launch_bounds__(256) void conv_f2b_k(const float* __restrict__ x,
                                                  unsigned short* __restrict__ y, int n4)
{
  const int i = blockIdx.x * 256 + threadIdx.x;
  if (i >= n4) return;
  const float4 v = ((const float4*)x)[i];
  ushort4 r;
  r.x = f2bf(v.x); r.y = f2bf(v.y); r.z = f2bf(v.z); r.w = f2bf(v.w);
  ((ushort4*)y)[i] = r;
}

// batched (L=5) transpose-convert: Wt[l][n][k] = bf16(W[l][k][colOff+n]), K=512
__global__ __launch_bounds__(256) void conv_wT_k(
    const float* __restrict__ W, unsigned short* __restrict__ Wt,
    int N, int ldW, int colOff, long wLS, long oLS)
{
  const int idx = blockIdx.x * 256 + threadIdx.x;
  const int per = N * 512;
  if (idx >= 5 * per) return;
  const int l = idx / per;
  const int r = idx - l * per;
  const int n = r >> 9;
  const int k = r & 511;
  Wt[l * oLS + (size_t)n * 512 + k] = f2bf(W[l * wLS + (size_t)k * ldW + colOff + n]);
}

// cb2[l][0..1280) = b1[l]@W2[l] + b2[l];  b34c[l][0..256) = b3[l]@W4[l] + b4[l]
__global__ __launch_bounds__(256) void biascomp_k(
    const float* __restrict__ b1, const float* __restrict__ W2, const float* __restrict__ b2,
    const float* __restrict__ b3, const float* __restrict__ W4, const float* __restrict__ b4,
    float* __restrict__ cb2, float* __restrict__ b34c)
{
  const int idx = blockIdx.x * 256 + threadIdx.x;
  if (idx < 5 * 1280){
    const int l = idx / 1280, n = idx - l * 1280;
    float s = b2[l * 1280 + n];
    for (int k = 0; k < 512; ++k)
      s += b1[l * 512 + k] * W2[(size_t)l * 512 * 1280 + (size_t)k * 1280 + n];
    cb2[idx] = s;
  } else if (idx < 5 * 1280 + 5 * 256){
    const int j = idx - 6400;
    const int l = j / 256, n = j - l * 256;
    float s = b4[l * 256 + n];
    for (int k = 0; k < 512; ++k)
      s += b3[l * 512 + k] * W4[(size_t)l * 512 * 256 + (size_t)k * 256 + n];
    b34c[j] = s;
  }
}

// c1p[l][n] = c1[l]@W34c[l][:,n],  c2p[l][n] = c2[l]@W34c[l][:,n]   (W34T bf16 [l][n][k])
__global__ __launch_bounds__(256) void compose_c_k(
    const float* __restrict__ cb2, const unsigned short* __restrict__ W34T,
    float* __restrict__ c1p, float* __restrict__ c2p)
{
  const int idx = blockIdx.x * 256 + threadIdx.x;
  if (idx >= 5 * 256) return;
  const int l = idx >> 8, n = idx & 255;
  const unsigned short* wr = W34T + ((size_t)l * 256 + n) * 512;
  float a = 0.f, b = 0.f;
  for (int k = 0; k < 512; ++k){
    const float w = bf2f(wr[k]);
    a += cb2[l * 1280 + k] * w;
    b += cb2[l * 1280 + 768 + k] * w;
  }
  c1p[idx] = a;
  c2p[idx] = b;
}

extern "C" void kernel_launch(void* const* d_in, const int* in_sizes, int n_in,
                              void* d_out, int out_size, void* d_ws, size_t ws_size,
                              hipStream_t stream)
{
  const float* obj_in  = (const float*)d_in[0];
  const float* pred_in = (const float*)d_in[1];
  const int*   edges   = (const int*)d_in[2];
  const float* W1 = (const float*)d_in[3];
  const float* b1 = (const float*)d_in[4];
  const float* W2 = (const float*)d_in[5];
  const float* b2 = (const float*)d_in[6];
  const float* W3 = (const float*)d_in[7];
  const float* b3 = (const float*)d_in[8];
  const float* W4 = (const float*)d_in[9];
  const float* b4 = (const float*)d_in[10];
  float* out = (float*)d_out;

  char* p = (char*)d_ws;
  auto alloc = [&](size_t bytes){ char* r = p; p += (bytes + 255) & ~(size_t)255; return r; };

  // weight staging (bf16)
  unsigned short* W1bf  = (unsigned short*)alloc((size_t)5 * 768 * 512 * 2);
  unsigned short* W2pT  = (unsigned short*)alloc((size_t)5 * 256 * 512 * 2);
  unsigned short* W2sT  = (unsigned short*)alloc((size_t)5 * 512 * 512 * 2);
  unsigned short* W2oT  = (unsigned short*)alloc((size_t)5 * 512 * 512 * 2);
  unsigned short* W3bf  = (unsigned short*)alloc((size_t)5 * 512 * 512 * 2);
  unsigned short* W4T   = (unsigned short*)alloc((size_t)5 * 256 * 512 * 2);
  // composed weights
  unsigned short* Wso_rm = (unsigned short*)alloc((size_t)5 * 1536 * 512 * 2); // W1@[W2s;W2o], row-major
  unsigned short* W34T   = (unsigned short*)alloc((size_t)5 * 256 * 512 * 2);  // (W3@W4)^T
  unsigned short* WWT    = (unsigned short*)alloc((size_t)5 * 256 * 1536 * 2); // (Wso@W34)^T
  unsigned short* WpSOT  = (unsigned short*)alloc((size_t)5 * 512 * 256 * 2);  // [Wp_s|Wp_o]^T
  unsigned short* WpPT   = (unsigned short*)alloc((size_t)5 * 256 * 256 * 2);  // Wp_p^T
  float* cb2  = (float*)alloc((size_t)5 * 1280 * 4);
  float* b34c = (float*)alloc((size_t)5 * 256 * 4);
  float* c1p  = (float*)alloc((size_t)5 * 256 * 4);
  float* c2p  = (float*)alloc((size_t)5 * 256 * 4);
  // activations
  unsigned short* objA    = (unsigned short*)alloc((size_t)NOBJ * DD * 2);   // 10.2 MB
  unsigned short* objB    = (unsigned short*)alloc((size_t)NOBJ * DD * 2);   // 10.2 MB
  unsigned short* pred_bf = (unsigned short*)alloc((size_t)NTRI * DD * 2);   // 30.7 MB
  unsigned short* tSO     = (unsigned short*)alloc((size_t)NOBJ * 1536 * 2); // 61.4 MB
  // overlays into tSO (dead after GEMM_A):
  unsigned short* objSO = tSO;                                   // 20.5 MB
  unsigned short* predP = tSO + (size_t)NOBJ * 512;              // 30.7 MB
  // CSR
  int2* eidx  = (int2*)alloc((size_t)NTRI * 8);
  int*  offs  = (int*)alloc((NOBJ + 1) * 4);
  int2* slots = (int2*)alloc((size_t)2 * NTRI * 8);
  int* cnt_s  = (int*)alloc(NOBJ * 4);
  int* cnt_o  = (int*)alloc(NOBJ * 4);
  int* cursor = (int*)alloc(NOBJ * 4);
  int* flag   = (int*)alloc(256);

  // ---- CSR preamble (edges are layer-invariant) ----
  hipMemsetAsync(cnt_s, 0, NOBJ * 4, stream);
  hipMemsetAsync(cnt_o, 0, NOBJ * 4, stream);
  hipMemsetAsync(flag, 0, 4, stream);
  const int EB = (NTRI + 255) / 256;
  detect_k<<<EB, 256, 0, stream>>>(edges, flag);
  norm_k<<<EB, 256, 0, stream>>>(edges, flag, eidx);
  deg_k<<<EB, 256, 0, stream>>>(eidx, cnt_s, cnt_o);
  scan_k<<<1, 1024, 0, stream>>>(cnt_s, cnt_o, offs);
  hipMemcpyAsync(cursor, offs, NOBJ * 4, hipMemcpyDeviceToDevice, stream);
  fill_k<<<EB, 256, 0, stream>>>(eidx, cursor, slots);

  // ---- inputs -> bf16 ----
  conv_f2b_k<<<(NOBJ * DD / 4 + 255) / 256, 256, 0, stream>>>(obj_in, objA, NOBJ * DD / 4);
  conv_f2b_k<<<(NTRI * DD / 4 + 255) / 256, 256, 0, stream>>>(pred_in, pred_bf, NTRI * DD / 4);

  // ---- weight staging ----
  conv_f2b_k<<<(5 * 768 * 512 / 4 + 255) / 256, 256, 0, stream>>>(W1, W1bf, 5 * 768 * 512 / 4);
  conv_f2b_k<<<(5 * 512 * 512 / 4 + 255) / 256, 256, 0, stream>>>(W3, W3bf, 5 * 512 * 512 / 4);
  conv_wT_k<<<(5 * 256 * 512 + 255) / 256, 256, 0, stream>>>(W2, W2pT, 256, 1280, 512, 512L*1280, 256L*512);
  conv_wT_k<<<(5 * 512 * 512 + 255) / 256, 256, 0, stream>>>(W2, W2sT, 512, 1280, 0,   512L*1280, 512L*512);
  conv_wT_k<<<(5 * 512 * 512 + 255) / 256, 256, 0, stream>>>(W2, W2oT, 512, 1280, 768, 512L*1280, 512L*512);
  conv_wT_k<<<(5 * 256 * 512 + 255) / 256, 256, 0, stream>>>(W4, W4T,  256, 256,  0,   512L*256,  256L*512);
  biascomp_k<<<30, 256, 0, stream>>>(b1, W2, b2, b3, W4, b4, cb2, b34c);

  // ---- weight composition GEMMs (grid.z = 5 layers) ----
  // Wso_rm rows [0,768) = W1@W2s (row-major)
  gemm_k<5><<<dim3(4, 6, 5), 256, 0, stream>>>(W1bf, W2sT, nullptr, nullptr, nullptr, nullptr, nullptr,
      Wso_rm, 768, 512, 512, 0, 768L*512, 512L*512, 1536L*512);
  // Wso_rm rows [768,1536) = W1@W2o
  gemm_k<5><<<dim3(4, 6, 5), 256, 0, stream>>>(W1bf, W2oT, nullptr, nullptr, nullptr, nullptr, nullptr,
      Wso_rm + (size_t)768*512, 768, 512, 512, 0, 768L*512, 512L*512, 1536L*512);
  // W34T = (W3@W4)^T
  gemm_k<3><<<dim3(2, 4, 5), 256, 0, stream>>>(W3bf, W4T, nullptr, nullptr, nullptr, nullptr, nullptr,
      W34T, 512, 512, 256, 512, 512L*512, 256L*512, 256L*512);
  // WWT = (Wso @ W34)^T   [1536x512 @ 512x256]
  gemm_k<3><<<dim3(2, 12, 5), 256, 0, stream>>>(Wso_rm, W34T, nullptr, nullptr, nullptr, nullptr, nullptr,
      WWT, 1536, 512, 256, 1536, 1536L*512, 256L*512, 256L*1536);
  // WpSOT[n<256] = (W1[0:256]@W2p)^T ; [n>=256] = (W1[512:768]@W2p)^T
  gemm_k<3><<<dim3(2, 2, 5), 256, 0, stream>>>(W1bf, W2pT, nullptr, nullptr, nullptr, nullptr, nullptr,
      WpSOT, 256, 512, 256, 256, 768L*512, 256L*512, 512L*256);
  gemm_k<3><<<dim3(2, 2, 5), 256, 0, stream>>>(W1bf + (size_t)512*512, W2pT, nullptr, nullptr, nullptr, nullptr, nullptr,
      WpSOT + (size_t)256*256, 256, 512, 256, 256, 768L*512, 256L*512, 512L*256);
  // WpPT = (W1[256:512]@W2p)^T
  gemm_k<3><<<dim3(2, 2, 5), 256, 0, stream>>>(W1bf + (size_t)256*512, W2pT, nullptr, nullptr, nullptr, nullptr, nullptr,
      WpPT, 256, 512, 256, 256, 768L*512, 256L*512, 256L*256);
  // composed epilogue biases
  compose_c_k<<<5, 256, 0, stream>>>(cb2, W34T, c1p, c2p);

  // ---- layers ----
  unsigned short* objbuf[2] = { objA, objB };
  int cur = 0;
  for (int l = 0; l < 5; ++l){
    const unsigned short* objc = objbuf[cur];
    // tSO = role-split t-space segment sums
    pool_t_k<<<NOBJ, 256, 0, stream>>>(objc, pred_bf, offs, slots, cnt_s, cnt_o, tSO);
    // new_obj = (tSO@WW + ns*c1p + no*c2p)/max(deg,1) + b34c   (20000x1536x256)
    if (l < 4)
      gemm_k<2><<<dim3(2, 157), 256, 0, stream>>>(tSO, WWT + (size_t)l*256*1536,
          c1p + l*256, c2p + l*256, b34c + l*256, cnt_s, cnt_o,
          objbuf[cur ^ 1], NOBJ, 1536, DD, 0, 0, 0, 0);
    else
      gemm_k<6><<<dim3(2, 157), 256, 0, stream>>>(tSO, WWT + (size_t)l*256*1536,
          c1p + l*256, c2p + l*256, b34c + l*256, cnt_s, cnt_o,
          out, NOBJ, 1536, DD, 0, 0, 0, 0);
    // objSO = obj @ [Wp_s|Wp_o]   (20000x256x512) — overlays tSO (dead now)
    gemm_k<5><<<dim3(4, 157), 256, 0, stream>>>(objc, WpSOT + (size_t)l*512*256,
        nullptr, nullptr, nullptr, nullptr, nullptr, objSO, NOBJ, 256, 512, 0, 0, 0, 0);
    // predP = pred @ Wp_p + b12p   (60000x256x256)
    gemm_k<0><<<dim3(2, 469), 256, 0, stream>>>(pred_bf, WpPT + (size_t)l*256*256,
        cb2 + (size_t)l*1280 + 512, nullptr, nullptr, nullptr, nullptr,
        predP, NTRI, 256, DD, 0, 0, 0, 0);
    // new_pred = predP + gather(objSO)
    if (l < 4)
      add_k<0><<<(NTRI * 64 + 255) / 256, 256, 0, stream>>>(predP, objSO, eidx, pred_bf);
    else
      add_k<1><<<(NTRI * 64 + 255) / 256, 256, 0, stream>>>(predP, objSO, eidx, out + (size_t)NOBJ * DD);
    cur ^= 1;
  }
}